// Round 3
// baseline (4339.255 us; speedup 1.0000x reference)
//
#include <hip/hip_runtime.h>
#include <hip/hip_bf16.h>
#include <hip/hip_fp8.h>
#include <math.h>

// Encoder GRU, B=8192 T=256 H=512 — sync-free state-resident, v6.
// v5 schedule (dbuf state, one barrier/step, lgkmcnt-only wait, ping-pong B,
// paired dwordx4 B loads, setprio) + hardware fp8 converts:
//  - epilogue pack: DPP xor1 swap -> v_cvt_pk_fp8_f32 (1 instr for the
//    ordered byte pair) -> DPP xor2 + select-merge -> 1-in-4 dword write.
//  - colb: raw LDS byte + v_cvt_f32_fp8 (1 instr), hoisted above the MFMA
//    loop so the LDS latency hides under the B-stream prologue.
// Motivation: v5 counters showed additive windows MFMA 5.6us + VALU 8.0us
// per step; inherent gate math is only ~2us of VALU -> software fp8
// conversion (hip_fp8.h bit-twiddling) suspected as the bulk of the rest.
// d_in: x(B,T), kmforenc(T), dense_kernel(1,H), dense_bias(H),
//       gru_kernel(H,3H), gru_recurrent(H,3H), gru_bias(2,3H)

constexpr int B_  = 8192;
constexpr int T_  = 256;
constexpr int H_  = 512;
constexpr int H3_ = 1536;
constexpr size_t BH = (size_t)B_ * H_;
constexpr int ROWS = 32;

typedef float f32x4 __attribute__((ext_vector_type(4)));
typedef long  lx2   __attribute__((ext_vector_type(2)));

__device__ __forceinline__ unsigned char f2e4m3(float f) {
    __hip_fp8_e4m3 v(f); return v.__x;
}
// swizzled byte offset into one fp8 state plane [32 rows][512 cols]
__device__ __forceinline__ int swz(int row, int col) {
    return (row * 512 + col) ^ ((row & 15) << 3);
}
__device__ __forceinline__ float fast_sigmoid(float v) {
    return __builtin_amdgcn_rcpf(1.f + __expf(-v));
}
__device__ __forceinline__ float fast_tanh(float v) {
    float a = fabsf(v);
    float e = __expf(-2.f * a);
    float t = (1.f - e) * __builtin_amdgcn_rcpf(1.f + e);
    return copysignf(t, v);
}

// wx[j] = sum_h dense_kernel[h]*gru_kernel[h,j]
// cc[j] = sum_h dense_bias[h]*gru_kernel[h,j] + gru_bias[0][j]
__global__ void prep_wx(const float* __restrict__ dk,
                        const float* __restrict__ db,
                        const float* __restrict__ K,
                        const float* __restrict__ gb,
                        float* __restrict__ wx,
                        float* __restrict__ cc) {
    int j = blockIdx.x * blockDim.x + threadIdx.x;
    if (j >= H3_) return;
    float a = 0.f, c = 0.f;
    for (int h = 0; h < H_; ++h) {
        float kv = K[(size_t)h * H3_ + j];
        a = fmaf(dk[h], kv, a);
        c = fmaf(db[h], kv, c);
    }
    wx[j] = a;
    cc[j] = c + gb[j];
}

// Pack R (H x 3H row-major) into per-(kc,w) fragment-PAIR blocks so one
// dwordx4 per lane fetches two MFMA B fragments:
//   pair block (kc,w,p): 128 ulongs; lane L holds ulongs [2L, 2L+1] =
//   frag f=2p and f=2p+1 lane-L data.
//   frag f: n = g*512 + w*32 + q*16 + (lane&15), k = kc*32 + 8*(lane>>4)+e,
//   with g=f>>1, q=f&1 (p==g, j==q).
__global__ void pack_Rf8(const float* __restrict__ R,
                         unsigned long long* __restrict__ Rp) {
    int idx  = blockIdx.x * 256 + threadIdx.x;    // < 98304
    int lane = idx & 63;
    int fi   = idx >> 6;                          // 0..1535
    int f    = fi % 6;
    int rest = fi / 6;                            // kc*16 + w
    int g    = f >> 1, q = f & 1;
    int w    = rest & 15;
    int n    = g * 512 + w * 32 + q * 16 + (lane & 15);
    int kb   = (rest >> 4) * 32 + 8 * (lane >> 4);
    unsigned long long v = 0;
    #pragma unroll
    for (int e = 0; e < 8; ++e)
        v |= (unsigned long long)f2e4m3(R[(size_t)(kb + e) * H3_ + n]) << (8 * e);
    Rp[(size_t)(rest * 3 + g) * 128 + 2 * lane + q] = v;
}

__global__ __launch_bounds__(1024, 4) void gru_f8(
    const float* __restrict__ x, const float* __restrict__ km,
    const unsigned long long* __restrict__ Rp,
    const float* __restrict__ wx, const float* __restrict__ cc,
    const float* __restrict__ b1,
    float* __restrict__ out0, float* __restrict__ out1)
{
    __shared__ __align__(16) unsigned char st[2][ROWS * 512]; // dbuf fp8 state
    __shared__ float rkm[T_];

    const int tid  = threadIdx.x;
    const int lane = tid & 63;
    const int w    = tid >> 6;                    // wave 0..15 -> cols [w*32,+32)
    const int l15  = lane & 15;
    const int lh   = lane >> 4;                   // 0..3
    const int row0 = blockIdx.x * ROWS;
    const bool odd1 = (l15 & 1) != 0;
    const bool odd2 = (l15 & 2) != 0;

    if (tid < T_) rkm[tid] = 1.f / km[tid];

    // per-thread gate constants (loop-invariant)
    const int jcq[2] = { w * 32 + l15, w * 32 + 16 + l15 };
    float wxz[2], wxr[2], wxh[2], czc[2], crc[2], cch[2], b1h[2];
    #pragma unroll
    for (int q = 0; q < 2; ++q) {
        int jc = jcq[q];
        wxz[q] = wx[jc];  wxr[q] = wx[512 + jc];  wxh[q] = wx[1024 + jc];
        czc[q] = cc[jc]        + b1[jc];
        crc[q] = cc[512 + jc]  + b1[512 + jc];
        cch[q] = cc[1024 + jc];
        b1h[q] = b1[1024 + jc];
    }

    float hprev[2][2][4];                         // [q][mi][rr] fp32 carry
    #pragma unroll
    for (int q = 0; q < 2; ++q)
        #pragma unroll
        for (int mi = 0; mi < 2; ++mi)
            #pragma unroll
            for (int rr = 0; rr < 4; ++rr) hprev[q][mi][rr] = 0.f;

    // B stream: pair block stride 128 ulongs, kc stride 16*3*128 = 6144
    const unsigned long long* wb = Rp + (size_t)w * 384 + 2 * lane;

    __syncthreads();   // rkm visible

    // depth-1 ping-pong: B0 enters each step holding kc=0 (loaded at the
    // previous step's kc=14 phase B wrap, flying through epilogue+barrier).
    lx2 B0[3], B1[3];
    #pragma unroll
    for (int p = 0; p < 3; ++p)
        B0[p] = *(const lx2*)(wb + p * 128);      // kc=0 (for t=1)

    #pragma unroll 1
    for (int t = 0; t < T_; ++t) {
        const char* rd = (const char*)st[t & 1];           // old state
        char*       wr = (char*)st[(t & 1) ^ 1];           // new state

        // colb: column t of old state (x column 0 at t=0), hoisted so LDS
        // latency hides before/under the MFMA loop. HW cvt: 1 instr/byte.
        const float rk = rkm[t];
        float colb[2][4];
        #pragma unroll
        for (int mi = 0; mi < 2; ++mi)
            #pragma unroll
            for (int rr = 0; rr < 4; ++rr) {
                const int brow = mi * 16 + lh * 4 + rr;
                if (t == 0) {
                    colb[mi][rr] = x[(size_t)(row0 + brow) * T_] * rk;
                } else {
                    int braw = ((const unsigned char*)rd)[swz(brow, t)];
                    colb[mi][rr] =
                        __builtin_amdgcn_cvt_f32_fp8(braw, 0) * rk;
                }
            }

        f32x4 acc[6][2];
        #pragma unroll
        for (int f = 0; f < 6; ++f) {
            acc[f][0] = (f32x4){0.f, 0.f, 0.f, 0.f};
            acc[f][1] = (f32x4){0.f, 0.f, 0.f, 0.f};
        }

        if (t > 0) {
            #pragma unroll 1
            for (int kc = 0; kc < 16; kc += 2) {
                // phase A: prefetch kc+1 -> B1, compute kc with B0
                #pragma unroll
                for (int p = 0; p < 3; ++p)
                    B1[p] = *(const lx2*)(wb + (size_t)(kc + 1) * 6144 + p * 128);
                long A0 = *(const long*)(rd + swz(l15,      kc * 32 + lh * 8));
                long A1 = *(const long*)(rd + swz(l15 + 16, kc * 32 + lh * 8));
                __builtin_amdgcn_s_setprio(1);
                #pragma unroll
                for (int p = 0; p < 3; ++p) {
                    #pragma unroll
                    for (int j = 0; j < 2; ++j) {
                        const int f = 2 * p + j;
                        acc[f][0] = __builtin_amdgcn_mfma_f32_16x16x32_fp8_fp8(
                            A0, B0[p][j], acc[f][0], 0, 0, 0);
                        acc[f][1] = __builtin_amdgcn_mfma_f32_16x16x32_fp8_fp8(
                            A1, B0[p][j], acc[f][1], 0, 0, 0);
                    }
                }
                __builtin_amdgcn_s_setprio(0);
                // phase B: prefetch (kc+2)&15 -> B0 (wraps to next step's
                // kc=0 at kc==14 — flies through epilogue + barrier).
                #pragma unroll
                for (int p = 0; p < 3; ++p)
                    B0[p] = *(const lx2*)(wb + (size_t)((kc + 2) & 15) * 6144 + p * 128);
                A0 = *(const long*)(rd + swz(l15,      (kc + 1) * 32 + lh * 8));
                A1 = *(const long*)(rd + swz(l15 + 16, (kc + 1) * 32 + lh * 8));
                __builtin_amdgcn_s_setprio(1);
                #pragma unroll
                for (int p = 0; p < 3; ++p) {
                    #pragma unroll
                    for (int j = 0; j < 2; ++j) {
                        const int f = 2 * p + j;
                        acc[f][0] = __builtin_amdgcn_mfma_f32_16x16x32_fp8_fp8(
                            A0, B1[p][j], acc[f][0], 0, 0, 0);
                        acc[f][1] = __builtin_amdgcn_mfma_f32_16x16x32_fp8_fp8(
                            A1, B1[p][j], acc[f][1], 0, 0, 0);
                    }
                }
                __builtin_amdgcn_s_setprio(0);
            }
        }

        // gates + state update; writes new plane (wr). HW fp8 pack:
        // DPP xor1 swap -> cvt_pk_fp8_f32 -> DPP xor2 -> select-merge.
        #pragma unroll
        for (int mi = 0; mi < 2; ++mi) {
            #pragma unroll
            for (int rr = 0; rr < 4; ++rr) {
                const int brow = mi * 16 + lh * 4 + rr;
                const float cb = colb[mi][rr];
                #pragma unroll
                for (int q = 0; q < 2; ++q) {
                    float z   = fast_sigmoid(fmaf(cb, wxz[q], czc[q])
                                             + acc[q][mi][rr]);
                    float r   = fast_sigmoid(fmaf(cb, wxr[q], crc[q])
                                             + acc[2 + q][mi][rr]);
                    float mhh = acc[4 + q][mi][rr] + b1h[q];
                    float hh  = fast_tanh(fmaf(r, mhh, fmaf(cb, wxh[q], cch[q])));
                    float hn  = fmaf(z, hprev[q][mi][rr] - hh, hh);
                    hprev[q][mi][rr] = hn;
                    // assemble 4 consecutive cols (across l15 quads):
                    float nb = __shfl_xor(hn, 1);          // DPP quad xor1
                    float lo = odd1 ? nb : hn;
                    float hi = odd1 ? hn : nb;
                    unsigned int w16 = (unsigned int)
                        __builtin_amdgcn_cvt_pk_fp8_f32(lo, hi, 0, false);
                    unsigned int v16 = (unsigned int)__shfl_xor((int)w16, 2);
                    unsigned int w32 = (odd2 ? v16 : w16)
                                     | ((odd2 ? w16 : v16) << 16);
                    if ((l15 & 3) == 0)
                        *(unsigned int*)(wr + swz(brow, w * 32 + q * 16 + l15)) = w32;
                }
            }
        }

        // ONE barrier/step: wait LDS ops only — B-stream globals in flight.
        asm volatile("s_waitcnt lgkmcnt(0)" ::: "memory");
        __builtin_amdgcn_s_barrier();
        asm volatile("" ::: "memory");
    }

    // final state from fp32 register carry -> both output halves
    #pragma unroll
    for (int q = 0; q < 2; ++q)
        #pragma unroll
        for (int mi = 0; mi < 2; ++mi)
            #pragma unroll
            for (int rr = 0; rr < 4; ++rr) {
                int brow = mi * 16 + lh * 4 + rr;
                size_t o = (size_t)(row0 + brow) * H_ + jcq[q];
                float v = hprev[q][mi][rr];
                out0[o] = v;
                out1[o] = v;
            }
}

extern "C" void kernel_launch(void* const* d_in, const int* in_sizes, int n_in,
                              void* d_out, int out_size, void* d_ws, size_t ws_size,
                              hipStream_t stream) {
    const float* x  = (const float*)d_in[0];
    const float* km = (const float*)d_in[1];
    const float* dk = (const float*)d_in[2];
    const float* db = (const float*)d_in[3];
    const float* K  = (const float*)d_in[4];
    const float* R  = (const float*)d_in[5];
    const float* gb = (const float*)d_in[6];

    float* out  = (float*)d_out;
    float* out1 = out + BH;

    float* wx = (float*)d_ws;                     // 1536 f
    float* cc = wx + H3_;                         // 1536 f
    unsigned long long* Rp = (unsigned long long*)(cc + H3_);   // 768 KB

    prep_wx<<<dim3((H3_ + 255) / 256), 256, 0, stream>>>(dk, db, K, gb, wx, cc);
    pack_Rf8<<<dim3(384), 256, 0, stream>>>(R, Rp);

    gru_f8<<<dim3(256), dim3(1024), 0, stream>>>(
        x, km, Rp, wx, cc, gb + H3_, out, out1);
}

// Round 4
// 2934.961 us; speedup vs baseline: 1.4785x; 1.4785x over previous
//
#include <hip/hip_runtime.h>
#include <hip/hip_bf16.h>
#include <hip/hip_fp8.h>
#include <math.h>

// Encoder GRU, B=8192 T=256 H=512 — sync-free state-resident, v7.
// Structure = v5 EXACTLY (dbuf state, one barrier/step, lgkmcnt-only wait,
// ping-pong B, paired dwordx4 B loads, setprio, colb read inside epilogue).
// Only change vs v5: software fp8 conversions replaced IN PLACE by HW
// converts (v_cvt_f32_fp8 / v_cvt_pk_fp8_f32 + DPP shfl merge).
// v6 post-mortem: hoisting colb above the MFMA loop (the other v6 change)
// correlated with FETCH_SIZE 29MB->2.7GB and a 39% regression — reverted.
// d_in: x(B,T), kmforenc(T), dense_kernel(1,H), dense_bias(H),
//       gru_kernel(H,3H), gru_recurrent(H,3H), gru_bias(2,3H)

constexpr int B_  = 8192;
constexpr int T_  = 256;
constexpr int H_  = 512;
constexpr int H3_ = 1536;
constexpr size_t BH = (size_t)B_ * H_;
constexpr int ROWS = 32;

typedef float f32x4 __attribute__((ext_vector_type(4)));
typedef long  lx2   __attribute__((ext_vector_type(2)));

__device__ __forceinline__ unsigned char f2e4m3(float f) {
    __hip_fp8_e4m3 v(f); return v.__x;
}
// swizzled byte offset into one fp8 state plane [32 rows][512 cols]
__device__ __forceinline__ int swz(int row, int col) {
    return (row * 512 + col) ^ ((row & 15) << 3);
}
__device__ __forceinline__ float fast_sigmoid(float v) {
    return __builtin_amdgcn_rcpf(1.f + __expf(-v));
}
__device__ __forceinline__ float fast_tanh(float v) {
    float a = fabsf(v);
    float e = __expf(-2.f * a);
    float t = (1.f - e) * __builtin_amdgcn_rcpf(1.f + e);
    return copysignf(t, v);
}

// wx[j] = sum_h dense_kernel[h]*gru_kernel[h,j]
// cc[j] = sum_h dense_bias[h]*gru_kernel[h,j] + gru_bias[0][j]
__global__ void prep_wx(const float* __restrict__ dk,
                        const float* __restrict__ db,
                        const float* __restrict__ K,
                        const float* __restrict__ gb,
                        float* __restrict__ wx,
                        float* __restrict__ cc) {
    int j = blockIdx.x * blockDim.x + threadIdx.x;
    if (j >= H3_) return;
    float a = 0.f, c = 0.f;
    for (int h = 0; h < H_; ++h) {
        float kv = K[(size_t)h * H3_ + j];
        a = fmaf(dk[h], kv, a);
        c = fmaf(db[h], kv, c);
    }
    wx[j] = a;
    cc[j] = c + gb[j];
}

// Pack R (H x 3H row-major) into per-(kc,w) fragment-PAIR blocks so one
// dwordx4 per lane fetches two MFMA B fragments:
//   pair block (kc,w,p): 128 ulongs; lane L holds ulongs [2L, 2L+1] =
//   frag f=2p and f=2p+1 lane-L data.
//   frag f: n = g*512 + w*32 + q*16 + (lane&15), k = kc*32 + 8*(lane>>4)+e,
//   with g=f>>1, q=f&1 (p==g, j==q).
__global__ void pack_Rf8(const float* __restrict__ R,
                         unsigned long long* __restrict__ Rp) {
    int idx  = blockIdx.x * 256 + threadIdx.x;    // < 98304
    int lane = idx & 63;
    int fi   = idx >> 6;                          // 0..1535
    int f    = fi % 6;
    int rest = fi / 6;                            // kc*16 + w
    int g    = f >> 1, q = f & 1;
    int w    = rest & 15;
    int n    = g * 512 + w * 32 + q * 16 + (lane & 15);
    int kb   = (rest >> 4) * 32 + 8 * (lane >> 4);
    unsigned long long v = 0;
    #pragma unroll
    for (int e = 0; e < 8; ++e)
        v |= (unsigned long long)f2e4m3(R[(size_t)(kb + e) * H3_ + n]) << (8 * e);
    Rp[(size_t)(rest * 3 + g) * 128 + 2 * lane + q] = v;
}

__global__ __launch_bounds__(1024, 4) void gru_f8(
    const float* __restrict__ x, const float* __restrict__ km,
    const unsigned long long* __restrict__ Rp,
    const float* __restrict__ wx, const float* __restrict__ cc,
    const float* __restrict__ b1,
    float* __restrict__ out0, float* __restrict__ out1)
{
    __shared__ __align__(16) unsigned char st[2][ROWS * 512]; // dbuf fp8 state
    __shared__ float rkm[T_];

    const int tid  = threadIdx.x;
    const int lane = tid & 63;
    const int w    = tid >> 6;                    // wave 0..15 -> cols [w*32,+32)
    const int l15  = lane & 15;
    const int lh   = lane >> 4;                   // 0..3
    const int row0 = blockIdx.x * ROWS;
    const bool odd1 = (l15 & 1) != 0;
    const bool odd2 = (l15 & 2) != 0;

    if (tid < T_) rkm[tid] = 1.f / km[tid];

    // per-thread gate constants (loop-invariant)
    const int jcq[2] = { w * 32 + l15, w * 32 + 16 + l15 };
    float wxz[2], wxr[2], wxh[2], czc[2], crc[2], cch[2], b1h[2];
    #pragma unroll
    for (int q = 0; q < 2; ++q) {
        int jc = jcq[q];
        wxz[q] = wx[jc];  wxr[q] = wx[512 + jc];  wxh[q] = wx[1024 + jc];
        czc[q] = cc[jc]        + b1[jc];
        crc[q] = cc[512 + jc]  + b1[512 + jc];
        cch[q] = cc[1024 + jc];
        b1h[q] = b1[1024 + jc];
    }

    float hprev[2][2][4];                         // [q][mi][rr] fp32 carry
    #pragma unroll
    for (int q = 0; q < 2; ++q)
        #pragma unroll
        for (int mi = 0; mi < 2; ++mi)
            #pragma unroll
            for (int rr = 0; rr < 4; ++rr) hprev[q][mi][rr] = 0.f;

    // B stream: pair block stride 128 ulongs, kc stride 16*3*128 = 6144
    const unsigned long long* wb = Rp + (size_t)w * 384 + 2 * lane;

    __syncthreads();   // rkm visible

    // depth-1 ping-pong: B0 enters each step holding kc=0 (loaded at the
    // previous step's kc=14 phase B wrap, flying through epilogue+barrier).
    lx2 B0[3], B1[3];
    #pragma unroll
    for (int p = 0; p < 3; ++p)
        B0[p] = *(const lx2*)(wb + p * 128);      // kc=0 (for t=1)

    #pragma unroll 1
    for (int t = 0; t < T_; ++t) {
        const char* rd = (const char*)st[t & 1];           // old state
        char*       wr = (char*)st[(t & 1) ^ 1];           // new state

        f32x4 acc[6][2];
        #pragma unroll
        for (int f = 0; f < 6; ++f) {
            acc[f][0] = (f32x4){0.f, 0.f, 0.f, 0.f};
            acc[f][1] = (f32x4){0.f, 0.f, 0.f, 0.f};
        }

        if (t > 0) {
            #pragma unroll 1
            for (int kc = 0; kc < 16; kc += 2) {
                // phase A: prefetch kc+1 -> B1, compute kc with B0
                #pragma unroll
                for (int p = 0; p < 3; ++p)
                    B1[p] = *(const lx2*)(wb + (size_t)(kc + 1) * 6144 + p * 128);
                long A0 = *(const long*)(rd + swz(l15,      kc * 32 + lh * 8));
                long A1 = *(const long*)(rd + swz(l15 + 16, kc * 32 + lh * 8));
                __builtin_amdgcn_s_setprio(1);
                #pragma unroll
                for (int p = 0; p < 3; ++p) {
                    #pragma unroll
                    for (int j = 0; j < 2; ++j) {
                        const int f = 2 * p + j;
                        acc[f][0] = __builtin_amdgcn_mfma_f32_16x16x32_fp8_fp8(
                            A0, B0[p][j], acc[f][0], 0, 0, 0);
                        acc[f][1] = __builtin_amdgcn_mfma_f32_16x16x32_fp8_fp8(
                            A1, B0[p][j], acc[f][1], 0, 0, 0);
                    }
                }
                __builtin_amdgcn_s_setprio(0);
                // phase B: prefetch (kc+2)&15 -> B0 (wraps to next step's
                // kc=0 at kc==14 — flies through epilogue + barrier).
                #pragma unroll
                for (int p = 0; p < 3; ++p)
                    B0[p] = *(const lx2*)(wb + (size_t)((kc + 2) & 15) * 6144 + p * 128);
                A0 = *(const long*)(rd + swz(l15,      (kc + 1) * 32 + lh * 8));
                A1 = *(const long*)(rd + swz(l15 + 16, (kc + 1) * 32 + lh * 8));
                __builtin_amdgcn_s_setprio(1);
                #pragma unroll
                for (int p = 0; p < 3; ++p) {
                    #pragma unroll
                    for (int j = 0; j < 2; ++j) {
                        const int f = 2 * p + j;
                        acc[f][0] = __builtin_amdgcn_mfma_f32_16x16x32_fp8_fp8(
                            A0, B1[p][j], acc[f][0], 0, 0, 0);
                        acc[f][1] = __builtin_amdgcn_mfma_f32_16x16x32_fp8_fp8(
                            A1, B1[p][j], acc[f][1], 0, 0, 0);
                    }
                }
                __builtin_amdgcn_s_setprio(0);
            }
        }

        // gates + state update; reads old plane (rd), writes new plane (wr).
        // Identical placement/order to v5; only the cvt instructions differ.
        const float rk = rkm[t];
        #pragma unroll
        for (int mi = 0; mi < 2; ++mi) {
            #pragma unroll
            for (int rr = 0; rr < 4; ++rr) {
                const int brow = mi * 16 + lh * 4 + rr;
                const float cb = ((t == 0)
                    ? x[(size_t)(row0 + brow) * T_]
                    : __builtin_amdgcn_cvt_f32_fp8(
                          (int)((const unsigned char*)rd)[swz(brow, t)], 0)) * rk;
                #pragma unroll
                for (int q = 0; q < 2; ++q) {
                    float z   = fast_sigmoid(fmaf(cb, wxz[q], czc[q])
                                             + acc[q][mi][rr]);
                    float r   = fast_sigmoid(fmaf(cb, wxr[q], crc[q])
                                             + acc[2 + q][mi][rr]);
                    float mhh = acc[4 + q][mi][rr] + b1h[q];
                    float hh  = fast_tanh(fmaf(r, mhh, fmaf(cb, wxh[q], cch[q])));
                    float hn  = fmaf(z, hprev[q][mi][rr] - hh, hh);
                    hprev[q][mi][rr] = hn;
                    // pack 4 consecutive cols (across l15 quads) into one dword:
                    // DPP xor1 swap -> HW cvt_pk (ordered pair) -> xor2 merge.
                    float nb = __shfl_xor(hn, 1);
                    float lo = odd1 ? nb : hn;
                    float hi = odd1 ? hn : nb;
                    unsigned int w16 = (unsigned int)
                        __builtin_amdgcn_cvt_pk_fp8_f32(lo, hi, 0, false);
                    unsigned int v16 = (unsigned int)__shfl_xor((int)w16, 2);
                    unsigned int w32 = (odd2 ? v16 : w16)
                                     | ((odd2 ? w16 : v16) << 16);
                    if ((l15 & 3) == 0)
                        *(unsigned int*)(wr + swz(brow, w * 32 + q * 16 + l15)) = w32;
                }
            }
        }

        // ONE barrier/step: wait LDS ops only — B-stream globals in flight.
        asm volatile("s_waitcnt lgkmcnt(0)" ::: "memory");
        __builtin_amdgcn_s_barrier();
        asm volatile("" ::: "memory");
    }

    // final state from fp32 register carry -> both output halves
    #pragma unroll
    for (int q = 0; q < 2; ++q)
        #pragma unroll
        for (int mi = 0; mi < 2; ++mi)
            #pragma unroll
            for (int rr = 0; rr < 4; ++rr) {
                int brow = mi * 16 + lh * 4 + rr;
                size_t o = (size_t)(row0 + brow) * H_ + jcq[q];
                float v = hprev[q][mi][rr];
                out0[o] = v;
                out1[o] = v;
            }
}

extern "C" void kernel_launch(void* const* d_in, const int* in_sizes, int n_in,
                              void* d_out, int out_size, void* d_ws, size_t ws_size,
                              hipStream_t stream) {
    const float* x  = (const float*)d_in[0];
    const float* km = (const float*)d_in[1];
    const float* dk = (const float*)d_in[2];
    const float* db = (const float*)d_in[3];
    const float* K  = (const float*)d_in[4];
    const float* R  = (const float*)d_in[5];
    const float* gb = (const float*)d_in[6];

    float* out  = (float*)d_out;
    float* out1 = out + BH;

    float* wx = (float*)d_ws;                     // 1536 f
    float* cc = wx + H3_;                         // 1536 f
    unsigned long long* Rp = (unsigned long long*)(cc + H3_);   // 768 KB

    prep_wx<<<dim3((H3_ + 255) / 256), 256, 0, stream>>>(dk, db, K, gb, wx, cc);
    pack_Rf8<<<dim3(384), 256, 0, stream>>>(R, Rp);

    gru_f8<<<dim3(256), dim3(1024), 0, stream>>>(
        x, km, Rp, wx, cc, gb + H3_, out, out1);
}

// Round 5
// 2863.120 us; speedup vs baseline: 1.5156x; 1.0251x over previous
//
#include <hip/hip_runtime.h>
#include <hip/hip_bf16.h>
#include <hip/hip_fp8.h>
#include <math.h>

// Encoder GRU, B=8192 T=256 H=512 — sync-free state-resident, v8.
// v7 (HW fp8 cvt, dbuf state, ping-pong B, paired dwordx4 B loads, setprio)
// + per-wave producer-consumer FLAGS instead of the block-wide barrier:
//   wave w's MFMA phase kc at step t reads state cols [kc*32,kc*32+32),
//   written only by wave kc's epilogue at step t-1 -> spin on
//   flag[kc] >= t (LDS). Producer: epilogue writes -> lgkmcnt(0) ->
//   flag[w]=t+1. kc order unchanged (0..15) -> bit-identical numerics.
//   Removes the lockstep dead window (epilogue VALU + barrier drain now
//   overlap other waves' MFMA phases).
// Safety: a wave enters its step-t epilogue only after seeing all flags>=t,
// so no wave can overwrite a plane another wave is still reading.
// d_in: x(B,T), kmforenc(T), dense_kernel(1,H), dense_bias(H),
//       gru_kernel(H,3H), gru_recurrent(H,3H), gru_bias(2,3H)

constexpr int B_  = 8192;
constexpr int T_  = 256;
constexpr int H_  = 512;
constexpr int H3_ = 1536;
constexpr size_t BH = (size_t)B_ * H_;
constexpr int ROWS = 32;

typedef float f32x4 __attribute__((ext_vector_type(4)));
typedef long  lx2   __attribute__((ext_vector_type(2)));

__device__ __forceinline__ unsigned char f2e4m3(float f) {
    __hip_fp8_e4m3 v(f); return v.__x;
}
// swizzled byte offset into one fp8 state plane [32 rows][512 cols]
__device__ __forceinline__ int swz(int row, int col) {
    return (row * 512 + col) ^ ((row & 15) << 3);
}
__device__ __forceinline__ float fast_sigmoid(float v) {
    return __builtin_amdgcn_rcpf(1.f + __expf(-v));
}
__device__ __forceinline__ float fast_tanh(float v) {
    float a = fabsf(v);
    float e = __expf(-2.f * a);
    float t = (1.f - e) * __builtin_amdgcn_rcpf(1.f + e);
    return copysignf(t, v);
}

// wx[j] = sum_h dense_kernel[h]*gru_kernel[h,j]
// cc[j] = sum_h dense_bias[h]*gru_kernel[h,j] + gru_bias[0][j]
__global__ void prep_wx(const float* __restrict__ dk,
                        const float* __restrict__ db,
                        const float* __restrict__ K,
                        const float* __restrict__ gb,
                        float* __restrict__ wx,
                        float* __restrict__ cc) {
    int j = blockIdx.x * blockDim.x + threadIdx.x;
    if (j >= H3_) return;
    float a = 0.f, c = 0.f;
    for (int h = 0; h < H_; ++h) {
        float kv = K[(size_t)h * H3_ + j];
        a = fmaf(dk[h], kv, a);
        c = fmaf(db[h], kv, c);
    }
    wx[j] = a;
    cc[j] = c + gb[j];
}

// Pack R (H x 3H row-major) into per-(kc,w) fragment-PAIR blocks so one
// dwordx4 per lane fetches two MFMA B fragments:
//   pair block (kc,w,p): 128 ulongs; lane L holds ulongs [2L, 2L+1] =
//   frag f=2p and f=2p+1 lane-L data.
//   frag f: n = g*512 + w*32 + q*16 + (lane&15), k = kc*32 + 8*(lane>>4)+e,
//   with g=f>>1, q=f&1 (p==g, j==q).
__global__ void pack_Rf8(const float* __restrict__ R,
                         unsigned long long* __restrict__ Rp) {
    int idx  = blockIdx.x * 256 + threadIdx.x;    // < 98304
    int lane = idx & 63;
    int fi   = idx >> 6;                          // 0..1535
    int f    = fi % 6;
    int rest = fi / 6;                            // kc*16 + w
    int g    = f >> 1, q = f & 1;
    int w    = rest & 15;
    int n    = g * 512 + w * 32 + q * 16 + (lane & 15);
    int kb   = (rest >> 4) * 32 + 8 * (lane >> 4);
    unsigned long long v = 0;
    #pragma unroll
    for (int e = 0; e < 8; ++e)
        v |= (unsigned long long)f2e4m3(R[(size_t)(kb + e) * H3_ + n]) << (8 * e);
    Rp[(size_t)(rest * 3 + g) * 128 + 2 * lane + q] = v;
}

__global__ __launch_bounds__(1024, 4) void gru_f8(
    const float* __restrict__ x, const float* __restrict__ km,
    const unsigned long long* __restrict__ Rp,
    const float* __restrict__ wx, const float* __restrict__ cc,
    const float* __restrict__ b1,
    float* __restrict__ out0, float* __restrict__ out1)
{
    __shared__ __align__(16) unsigned char st[2][ROWS * 512]; // dbuf fp8 state
    __shared__ float rkm[T_];
    __shared__ int flags[16];                     // steps completed per wave

    const int tid  = threadIdx.x;
    const int lane = tid & 63;
    const int w    = tid >> 6;                    // wave 0..15 -> cols [w*32,+32)
    const int l15  = lane & 15;
    const int lh   = lane >> 4;                   // 0..3
    const int row0 = blockIdx.x * ROWS;
    const bool odd1 = (l15 & 1) != 0;
    const bool odd2 = (l15 & 2) != 0;
    volatile int* vflag = (volatile int*)flags;

    if (tid < T_) rkm[tid] = 1.f / km[tid];
    if (tid < 16) flags[tid] = 0;

    // per-thread gate constants (loop-invariant)
    const int jcq[2] = { w * 32 + l15, w * 32 + 16 + l15 };
    float wxz[2], wxr[2], wxh[2], czc[2], crc[2], cch[2], b1h[2];
    #pragma unroll
    for (int q = 0; q < 2; ++q) {
        int jc = jcq[q];
        wxz[q] = wx[jc];  wxr[q] = wx[512 + jc];  wxh[q] = wx[1024 + jc];
        czc[q] = cc[jc]        + b1[jc];
        crc[q] = cc[512 + jc]  + b1[512 + jc];
        cch[q] = cc[1024 + jc];
        b1h[q] = b1[1024 + jc];
    }

    float hprev[2][2][4];                         // [q][mi][rr] fp32 carry
    #pragma unroll
    for (int q = 0; q < 2; ++q)
        #pragma unroll
        for (int mi = 0; mi < 2; ++mi)
            #pragma unroll
            for (int rr = 0; rr < 4; ++rr) hprev[q][mi][rr] = 0.f;

    // B stream: pair block stride 128 ulongs, kc stride 16*3*128 = 6144
    const unsigned long long* wb = Rp + (size_t)w * 384 + 2 * lane;

    __syncthreads();   // rkm + flags init visible (only barrier in kernel)

    // depth-1 ping-pong: B0 enters each step holding kc=0 (loaded at the
    // previous step's kc=14 phase B wrap, flying through epilogue).
    lx2 B0[3], B1[3];
    #pragma unroll
    for (int p = 0; p < 3; ++p)
        B0[p] = *(const lx2*)(wb + p * 128);      // kc=0 (for t=1)

    #pragma unroll 1
    for (int t = 0; t < T_; ++t) {
        const char* rd = (const char*)st[t & 1];           // old state
        char*       wr = (char*)st[(t & 1) ^ 1];           // new state

        f32x4 acc[6][2];
        #pragma unroll
        for (int f = 0; f < 6; ++f) {
            acc[f][0] = (f32x4){0.f, 0.f, 0.f, 0.f};
            acc[f][1] = (f32x4){0.f, 0.f, 0.f, 0.f};
        }

        if (t > 0) {
            #pragma unroll 1
            for (int kc = 0; kc < 16; kc += 2) {
                // phase A: prefetch kc+1 -> B1, compute kc with B0
                #pragma unroll
                for (int p = 0; p < 3; ++p)
                    B1[p] = *(const lx2*)(wb + (size_t)(kc + 1) * 6144 + p * 128);
                // wait for producer wave kc's step t-1 epilogue
                while (vflag[kc] < t) __builtin_amdgcn_s_sleep(1);
                asm volatile("" ::: "memory");
                long A0 = *(const long*)(rd + swz(l15,      kc * 32 + lh * 8));
                long A1 = *(const long*)(rd + swz(l15 + 16, kc * 32 + lh * 8));
                __builtin_amdgcn_s_setprio(1);
                #pragma unroll
                for (int p = 0; p < 3; ++p) {
                    #pragma unroll
                    for (int j = 0; j < 2; ++j) {
                        const int f = 2 * p + j;
                        acc[f][0] = __builtin_amdgcn_mfma_f32_16x16x32_fp8_fp8(
                            A0, B0[p][j], acc[f][0], 0, 0, 0);
                        acc[f][1] = __builtin_amdgcn_mfma_f32_16x16x32_fp8_fp8(
                            A1, B0[p][j], acc[f][1], 0, 0, 0);
                    }
                }
                __builtin_amdgcn_s_setprio(0);
                // phase B: prefetch (kc+2)&15 -> B0 (wraps to next step's
                // kc=0 at kc==14 — flies through the epilogue).
                #pragma unroll
                for (int p = 0; p < 3; ++p)
                    B0[p] = *(const lx2*)(wb + (size_t)((kc + 2) & 15) * 6144 + p * 128);
                while (vflag[kc + 1] < t) __builtin_amdgcn_s_sleep(1);
                asm volatile("" ::: "memory");
                A0 = *(const long*)(rd + swz(l15,      (kc + 1) * 32 + lh * 8));
                A1 = *(const long*)(rd + swz(l15 + 16, (kc + 1) * 32 + lh * 8));
                __builtin_amdgcn_s_setprio(1);
                #pragma unroll
                for (int p = 0; p < 3; ++p) {
                    #pragma unroll
                    for (int j = 0; j < 2; ++j) {
                        const int f = 2 * p + j;
                        acc[f][0] = __builtin_amdgcn_mfma_f32_16x16x32_fp8_fp8(
                            A0, B1[p][j], acc[f][0], 0, 0, 0);
                        acc[f][1] = __builtin_amdgcn_mfma_f32_16x16x32_fp8_fp8(
                            A1, B1[p][j], acc[f][1], 0, 0, 0);
                    }
                }
                __builtin_amdgcn_s_setprio(0);
            }
        }

        // gates + state update; reads old plane (rd), writes new plane (wr).
        const float rk = rkm[t];
        #pragma unroll
        for (int mi = 0; mi < 2; ++mi) {
            #pragma unroll
            for (int rr = 0; rr < 4; ++rr) {
                const int brow = mi * 16 + lh * 4 + rr;
                const float cb = ((t == 0)
                    ? x[(size_t)(row0 + brow) * T_]
                    : __builtin_amdgcn_cvt_f32_fp8(
                          (int)((const unsigned char*)rd)[swz(brow, t)], 0)) * rk;
                #pragma unroll
                for (int q = 0; q < 2; ++q) {
                    float z   = fast_sigmoid(fmaf(cb, wxz[q], czc[q])
                                             + acc[q][mi][rr]);
                    float r   = fast_sigmoid(fmaf(cb, wxr[q], crc[q])
                                             + acc[2 + q][mi][rr]);
                    float mhh = acc[4 + q][mi][rr] + b1h[q];
                    float hh  = fast_tanh(fmaf(r, mhh, fmaf(cb, wxh[q], cch[q])));
                    float hn  = fmaf(z, hprev[q][mi][rr] - hh, hh);
                    hprev[q][mi][rr] = hn;
                    // pack 4 consecutive cols (across l15 quads) into one dword:
                    // DPP xor1 swap -> HW cvt_pk (ordered pair) -> xor2 merge.
                    float nb = __shfl_xor(hn, 1);
                    float lo = odd1 ? nb : hn;
                    float hi = odd1 ? hn : nb;
                    unsigned int w16 = (unsigned int)
                        __builtin_amdgcn_cvt_pk_fp8_f32(lo, hi, 0, false);
                    unsigned int v16 = (unsigned int)__shfl_xor((int)w16, 2);
                    unsigned int w32 = (odd2 ? v16 : w16)
                                     | ((odd2 ? w16 : v16) << 16);
                    if ((l15 & 3) == 0)
                        *(unsigned int*)(wr + swz(brow, w * 32 + q * 16 + l15)) = w32;
                }
            }
        }

        // publish: all this wave's LDS reads (phases + colb) and writes done,
        // then raise flag. Consumers spin on it; no block barrier.
        asm volatile("s_waitcnt lgkmcnt(0)" ::: "memory");
        if (lane == 0) vflag[w] = t + 1;
    }

    // final state from fp32 register carry -> both output halves
    #pragma unroll
    for (int q = 0; q < 2; ++q)
        #pragma unroll
        for (int mi = 0; mi < 2; ++mi)
            #pragma unroll
            for (int rr = 0; rr < 4; ++rr) {
                int brow = mi * 16 + lh * 4 + rr;
                size_t o = (size_t)(row0 + brow) * H_ + jcq[q];
                float v = hprev[q][mi][rr];
                out0[o] = v;
                out1[o] = v;
            }
}

extern "C" void kernel_launch(void* const* d_in, const int* in_sizes, int n_in,
                              void* d_out, int out_size, void* d_ws, size_t ws_size,
                              hipStream_t stream) {
    const float* x  = (const float*)d_in[0];
    const float* km = (const float*)d_in[1];
    const float* dk = (const float*)d_in[2];
    const float* db = (const float*)d_in[3];
    const float* K  = (const float*)d_in[4];
    const float* R  = (const float*)d_in[5];
    const float* gb = (const float*)d_in[6];

    float* out  = (float*)d_out;
    float* out1 = out + BH;

    float* wx = (float*)d_ws;                     // 1536 f
    float* cc = wx + H3_;                         // 1536 f
    unsigned long long* Rp = (unsigned long long*)(cc + H3_);   // 768 KB

    prep_wx<<<dim3((H3_ + 255) / 256), 256, 0, stream>>>(dk, db, K, gb, wx, cc);
    pack_Rf8<<<dim3(384), 256, 0, stream>>>(R, Rp);

    gru_f8<<<dim3(256), dim3(1024), 0, stream>>>(
        x, km, Rp, wx, cc, gb + H3_, out, out1);
}